// Round 1
// baseline (617.635 us; speedup 1.0000x reference)
//
#include <hip/hip_runtime.h>
#include <hip/hip_bf16.h>

#define KREM 172
#define NDIM 11008        // 172 * 64
#define JPAD 176          // 11 * 16
#define KP_HAD 192        // padded K for hadB (6 * 32)
#define KP_Y 256          // padded K stride for swizzled Y^T in LDS

typedef __bf16 bf16x8 __attribute__((ext_vector_type(8)));
typedef float  f32x4  __attribute__((ext_vector_type(4)));
typedef float  f32x2  __attribute__((ext_vector_type(2)));

// had (172x172 fp32) -> hadB (176x192 bf16, zero padded), row-major,
// PRE-SCALED by 1/sqrt(11008) so stage 1 needs no per-element scale mul.
__global__ void prep_had_kernel(const float* __restrict__ had,
                                __bf16* __restrict__ hadB) {
  int idx = blockIdx.x * 256 + threadIdx.x;
  if (idx >= JPAD * KP_HAD) return;
  int j = idx / KP_HAD;
  int k = idx - j * KP_HAD;
  float v = (j < KREM && k < KREM) ? had[j * KREM + k] * 9.53115434e-3f : 0.0f;
  hadB[idx] = (__bf16)v;
}

__global__ void __launch_bounds__(256, 4) had_fused_kernel(
    const float* __restrict__ x, const __bf16* __restrict__ hadB,
    float* __restrict__ out) {
  // Swizzled Y^T: element (n,k) at Yt[n*KP_Y + ((k>>3)^(n>>3))*8 + (k&7)], 32 KB
  __shared__ __bf16 Yt[64 * KP_Y];

  const int tid  = threadIdx.x;
  const int wave = tid >> 6;
  const int lane = tid & 63;
  const size_t rowoff = (size_t)blockIdx.x * NDIM;
  const float* xr   = x + rowoff;
  float*       outr = out + rowoff;

  // Zero ONLY the k-pad slots (logical k in [172,192)). These physical slots
  // are address-disjoint from every stage-1 write, so no barrier is needed
  // between this and stage 1 — the single pre-stage-2 barrier covers both.
  if (tid < 64) {
    const int e = tid >> 3;                 // n>>3 for this row
    __bf16* row = Yt + tid * KP_Y;
    const f32x4 z4 = {0.f, 0.f, 0.f, 0.f};
    *(f32x4*)(row + (((22 ^ e) << 3)))     = z4;              // k 176..183
    *(f32x4*)(row + (((23 ^ e) << 3)))     = z4;              // k 184..191
    *(f32x2*)(row + (((21 ^ e) << 3)) + 4) = (f32x2){0.f, 0.f}; // k 172..175
  }

  // ---------------- Stage 1: FHT-64 per segment, fp32, on-load ----------------
  const int grp = tid >> 3;  // 0..31  (segment within pass)
  const int lid = tid & 7;   // lane within 8-lane segment group

#pragma unroll
  for (int p = 0; p < 6; ++p) {
    const int k = p * 32 + grp;
    if (k < KREM) {
      const float4* seg = (const float4*)(xr + k * 64 + lid * 8);
      float4 a = seg[0], b = seg[1];
      float v[8] = {a.x, a.y, a.z, a.w, b.x, b.y, b.z, b.w};
      // in-register butterfly stages (m-strides 1,2,4)
#pragma unroll
      for (int s = 1; s <= 4; s <<= 1) {
#pragma unroll
        for (int i = 0; i < 8; ++i) {
          if ((i & s) == 0) {
            float u0 = v[i], u1 = v[i + s];
            v[i] = u0 + u1;
            v[i + s] = u0 - u1;
          }
        }
      }
      // cross-lane stages (m-strides 8,16,32 -> lane masks 1,2,4)
      // v_new = t + sgn*v  (one FMA per element; sgn = +/-1 exact)
#pragma unroll
      for (int s = 1; s <= 4; s <<= 1) {
        const float sgn = (lid & s) ? -1.0f : 1.0f;
#pragma unroll
        for (int i = 0; i < 8; ++i) {
          float t = __shfl_xor(v[i], s, 64);
          v[i] = __builtin_fmaf(v[i], sgn, t);
        }
      }
      // write transposed + swizzled bf16 (scale already folded into hadB)
      const int kb = k >> 3, ko = k & 7;
      const int kbs = (kb ^ lid) << 3;   // n>>3 == lid
#pragma unroll
      for (int i = 0; i < 8; ++i) {
        Yt[(lid * 8 + i) * KP_Y + kbs + ko] = (__bf16)v[i];
      }
    }
  }
  __syncthreads();

  // ---------------- Stage 2: Z^T = Y^T(64x192) @ had^T(192x176) via MFMA ------
  // Sequential j-tiles: acc[4] live (16 VGPRs) instead of acc[3][4] (48) —
  // keeps the kernel comfortably under the 128-VGPR cap (no spill risk).
  const int l15 = lane & 15;
  const int q   = lane >> 4;
  const int njt = (wave < 3) ? 3 : 2;  // waves own jt = {w, w+4, w+8} (<11)

#pragma unroll 1
  for (int jl = 0; jl < njt; ++jl) {
    const int jt   = wave + jl * 4;
    const int jrow = jt * 16 + l15;
    const __bf16* hb = hadB + jrow * KP_HAD;
    f32x4 acc[4] = {};
    __builtin_amdgcn_s_setprio(1);
#pragma unroll
    for (int kc = 0; kc < 6; ++kc) {
      const int kbase = kc * 32 + q * 8;
      const bf16x8 bfr = *(const bf16x8*)&hb[kbase];
#pragma unroll
      for (int nt = 0; nt < 4; ++nt) {
        const int n  = nt * 16 + l15;
        const int kb = (kbase >> 3) ^ (n >> 3);
        const bf16x8 afr = *(const bf16x8*)&Yt[n * KP_Y + (kb << 3)];
        acc[nt] = __builtin_amdgcn_mfma_f32_16x16x32_bf16(afr, bfr, acc[nt],
                                                          0, 0, 0);
      }
    }
    __builtin_amdgcn_s_setprio(0);
    // epilogue: D[row=n=q*4+reg][col=j=l15] -> out[j*64 + n], contiguous float4
    if (jrow < KREM) {
#pragma unroll
      for (int nt = 0; nt < 4; ++nt) {
        *(f32x4*)(outr + jrow * 64 + nt * 16 + q * 4) = acc[nt];
      }
    }
  }
}

extern "C" void kernel_launch(void* const* d_in, const int* in_sizes, int n_in,
                              void* d_out, int out_size, void* d_ws, size_t ws_size,
                              hipStream_t stream) {
  const float* x   = (const float*)d_in[0];
  const float* had = (const float*)d_in[1];
  __bf16* hadB = (__bf16*)d_ws;                   // 176*192*2 = 67584 B
  float* out = (float*)d_out;
  const int rows = in_sizes[0] / NDIM;            // 8192

  hipLaunchKernelGGL(prep_had_kernel, dim3((JPAD * KP_HAD + 255) / 256),
                     dim3(256), 0, stream, had, hadB);
  hipLaunchKernelGGL(had_fused_kernel, dim3(rows), dim3(256), 0, stream,
                     x, hadB, out);
}